// Round 7
// baseline (92.535 us; speedup 1.0000x reference)
//
#include <hip/hip_runtime.h>
#include <hip/hip_bf16.h>

namespace {

constexpr int Nn = 2048;
constexpr int Hh = 16;
constexpr int Dd = 64;
constexpr int ROWSTR = Hh * Dd;      // 1024 floats between consecutive tokens
constexpr int KVB = 64;              // KV tile rows
constexpr int NTILES = Nn / KVB;     // 32
constexpr int QB = 64;               // q-rows per block (2 stripes x 32)
constexpr int NQT = Nn / QB;         // 32 q-tiles per (b,h)

typedef __bf16 bf16x8 __attribute__((ext_vector_type(8)));
typedef __bf16 bf16x4 __attribute__((ext_vector_type(4)));
typedef float  f32x16 __attribute__((ext_vector_type(16)));

// K tile: row-major [64][64] bf16, 128B rows, 16B-granule XOR swizzle (b128 reads)
__device__ __forceinline__ int swzK(int row, int colByte) {
  return (row * 128 + colByte) ^ ((row & 7) << 4);
}
// V^T tile: [d=64][kv=64] bf16, extra bit-3 XOR (b64 reads 2-way = free)
__device__ __forceinline__ int swzV(int row, int colByte) {
  return (row * 128 + colByte) ^ (((row & 7) << 4) | (((row >> 3) & 1) << 3));
}

struct KS { float4 k[8]; };   // 32 VGPR while live
struct VS { float v[32]; };   // 32 VGPR while live (disjoint lifetime from KS)

// 256 threads stage a PAIR of 64x64 KV tiles (128 kv rows) per interval.
__device__ __forceinline__ void issueK(const float* kp, int kv0, int tid, KS& s) {
#pragma unroll
  for (int it = 0; it < 8; ++it) {
    int idx = it * 256 + tid;
    int kvr = idx >> 4, c4 = idx & 15;              // kvr in [0,128)
    s.k[it] = *(const float4*)(kp + (size_t)(kv0 + kvr) * ROWSTR + c4 * 4);
  }
}
__device__ __forceinline__ void writeK(char* base, int tid, const KS& s) {
#pragma unroll
  for (int it = 0; it < 8; ++it) {
    int idx = it * 256 + tid;
    int kvr = idx >> 4, c4 = idx & 15;
    char* kb = base + (kvr >> 6) * 16384;           // parity tile slot
    bf16x4 w = { (__bf16)s.k[it].x, (__bf16)s.k[it].y,
                 (__bf16)s.k[it].z, (__bf16)s.k[it].w };
    *(bf16x4*)(kb + swzK(kvr & 63, c4 * 8)) = w;
  }
}
__device__ __forceinline__ void issueV(const float* vp, int kv0, int tid, VS& s) {
#pragma unroll
  for (int it = 0; it < 8; ++it) {
    int idx = it * 256 + tid;
    int d8 = idx & 63, kv4 = idx >> 6;              // kv4 in [0,32)
#pragma unroll
    for (int i2 = 0; i2 < 4; ++i2)
      s.v[it * 4 + i2] = vp[(size_t)(kv0 + kv4 * 4 + i2) * ROWSTR + d8];
  }
}
__device__ __forceinline__ void writeV(char* base, int tid, const VS& s) {
#pragma unroll
  for (int it = 0; it < 8; ++it) {
    int idx = it * 256 + tid;
    int d8 = idx & 63, kv4 = idx >> 6;
    char* vb = base + (kv4 >> 4) * 16384 + 8192;
    bf16x4 w = { (__bf16)s.v[it * 4 + 0], (__bf16)s.v[it * 4 + 1],
                 (__bf16)s.v[it * 4 + 2], (__bf16)s.v[it * 4 + 3] };
    *(bf16x4*)(vb + swzV(d8, (kv4 & 15) * 8)) = w;
  }
}

__global__ __launch_bounds__(256, 2) void fattn_kernel(
    const float* __restrict__ Qg, const float* __restrict__ Kg,
    const float* __restrict__ Vg, const int* __restrict__ flag,
    float* __restrict__ Og) {
  // [buf][parity]{K 8KB | V^T 8KB} = 64 KB -> exactly 2 blocks/CU.
  __shared__ __align__(16) char smem[2][2][16384];

  const int tid  = threadIdx.x;
  const int lane = tid & 63;
  const int wv   = tid >> 6;    // 0..3
  const int grp  = wv >> 1;     // KV parity: 0 = even tiles, 1 = odd tiles
  const int st   = wv & 1;      // q stripe (32 rows) within the 64-row q-tile
  const int l31  = lane & 31;
  const int g2   = lane >> 5;   // 0/1

  // grid 512 = 32 bh x 16 uniform pairs; bid&7 -> 4-head XCD group.
  const int bid = blockIdx.x;
  const int bh  = ((bid & 7) << 2) | ((bid >> 3) & 3);
  const int j   = (bid >> 5) & 15;    // pair index: q-tiles {31-j, j}
  const int b   = bh >> 4;
  const int h   = bh & 15;
  const int causal = flag[0];

  const size_t base = ((size_t)b * Nn * Hh + h) * Dd;
  const float* qp = Qg + base;
  const float* kp = Kg + base;
  const float* vp = Vg + base;
  float*       op = Og + base;

  const float SCALE = 0.125f * 1.44269504088896340736f;  // 1/sqrt(64) * log2(e)

  for (int pass = 0; pass < 2; ++pass) {
    const int Tq = pass ? j : (NQT - 1 - j);   // q-tile of 64 rows
    const int qs = Tq * QB + st * 32;          // wave's first q row
    // intervals (tile pairs) staged; per-grp computed count
    const int NI = causal ? ((Tq + 2) >> 1) : (NTILES / 2);
    const int nC = causal ? (grp == 0 ? (Tq / 2 + 1) : ((Tq + 1) / 2)) : (NTILES / 2);

    __syncthreads();   // previous pass's LDS reads (merge arena) complete

    // ---- Q fragments (contiguous k-slot map) ----
    bf16x8 qf[4];
#pragma unroll
    for (int dc = 0; dc < 4; ++dc) {
      const float* qrow = qp + (size_t)(qs + l31) * ROWSTR + dc * 16 + g2 * 8;
      float4 a = *(const float4*)qrow;
      float4 c = *(const float4*)(qrow + 4);
      qf[dc][0] = (__bf16)(a.x * SCALE); qf[dc][1] = (__bf16)(a.y * SCALE);
      qf[dc][2] = (__bf16)(a.z * SCALE); qf[dc][3] = (__bf16)(a.w * SCALE);
      qf[dc][4] = (__bf16)(c.x * SCALE); qf[dc][5] = (__bf16)(c.y * SCALE);
      qf[dc][6] = (__bf16)(c.z * SCALE); qf[dc][7] = (__bf16)(c.w * SCALE);
    }

    f32x16 acc0 = {};   // O cols 0..31 (col = l31)
    f32x16 acc1 = {};   // O cols 32..63
    float m_run = -INFINITY;
    float l_run = 0.0f;

    // ---- prologue: stage tile pair 0 into buf 0 ----
    {
      KS ks; issueK(kp, 0, tid, ks); writeK(&smem[0][0][0], tid, ks);
      VS vs; issueV(vp, 0, tid, vs); writeV(&smem[0][0][0], tid, vs);
    }

    for (int i = 0; i < NI; ++i) {
      __syncthreads();
      const bool pf = (i + 1 < NI);
      const bool doC = (i < nC);
      const char* kb = &smem[i & 1][grp][0];
      const char* vb = kb + 8192;
      char* nb = &smem[(i + 1) & 1][0][0];

      KS ks;
      if (pf) issueK(kp, (i + 1) * 128, tid, ks);  // drain hides under QK

      f32x16 s0, s1;
      bf16x8 pa[4];
      float mnew = m_run, rs = 0.0f, mt = -INFINITY;

      if (doC) {
        // ---- S^T = K . Q^T ----
        s0 = (f32x16){}; s1 = (f32x16){};
#pragma unroll
        for (int dc = 0; dc < 4; ++dc) {
          bf16x8 kf0 = *(const bf16x8*)(kb + swzK(l31,      32 * dc + 16 * g2));
          bf16x8 kf1 = *(const bf16x8*)(kb + swzK(32 + l31, 32 * dc + 16 * g2));
          s0 = __builtin_amdgcn_mfma_f32_32x32x16_bf16(kf0, qf[dc], s0, 0, 0, 0);
          s1 = __builtin_amdgcn_mfma_f32_32x32x16_bf16(kf1, qf[dc], s1, 0, 0, 0);
        }
        // ---- causal mask (this wave's diagonal tile only) ----
        if (causal && (2 * i + grp) == Tq) {
          const int kvb = Tq * KVB;
          const int qrow = qs + l31;
#pragma unroll
          for (int rr = 0; rr < 16; ++rr) {
            int rm = (rr & 3) + ((rr >> 2) << 3) + (g2 << 2);
            if (kvb + rm > qrow)      s0[rr] = -INFINITY;
            if (kvb + 32 + rm > qrow) s1[rr] = -INFINITY;
          }
        }
        // ---- max: pairwise tree ----
        float p8[8];
#pragma unroll
        for (int e = 0; e < 8; ++e)
          p8[e] = fmaxf(fmaxf(s0[e], s0[e + 8]), fmaxf(s1[e], s1[e + 8]));
        mt = fmaxf(fmaxf(fmaxf(p8[0], p8[1]), fmaxf(p8[2], p8[3])),
                   fmaxf(fmaxf(p8[4], p8[5]), fmaxf(p8[6], p8[7])));
        mt = fmaxf(mt, __shfl_xor(mt, 32));
        mnew = fmaxf(m_run, mt);
      }

      VS vs;
      if (pf) {
        writeK(nb, tid, ks);                        // K drained under QK
        issueV(vp, (i + 1) * 128, tid, vs);         // drain hides under softmax
      }

      if (doC) {
        // ---- exp + sum tree ----
#pragma unroll
        for (int rr = 0; rr < 16; ++rr) {
          s0[rr] = __builtin_amdgcn_exp2f(s0[rr] - mnew);
          s1[rr] = __builtin_amdgcn_exp2f(s1[rr] - mnew);
        }
        float q8[8];
#pragma unroll
        for (int e = 0; e < 8; ++e)
          q8[e] = (s0[e] + s0[e + 8]) + (s1[e] + s1[e + 8]);
        rs = ((q8[0] + q8[1]) + (q8[2] + q8[3])) + ((q8[4] + q8[5]) + (q8[6] + q8[7]));
        rs += __shfl_xor(rs, 32);
        if (__all(mt <= m_run)) {
          l_run += rs;
        } else {
          const float alpha = __builtin_amdgcn_exp2f(m_run - mnew);
#pragma unroll
          for (int rr = 0; rr < 16; ++rr) {
            float at = __shfl(alpha, (rr & 3) + ((rr >> 2) << 3) + (g2 << 2));
            acc0[rr] *= at;
            acc1[rr] *= at;
          }
          l_run = l_run * alpha + rs;
          m_run = mnew;
        }
        // ---- P fragments: pass-through of S^T regs (split-4 k-slot map) ----
#pragma unroll
        for (int kc = 0; kc < 4; ++kc) {
          const f32x16& sv = (kc < 2) ? s0 : s1;
          const int rbase = (kc & 1) * 8;
#pragma unroll
          for (int jj = 0; jj < 8; ++jj) pa[kc][jj] = (__bf16)sv[rbase + jj];
        }
      }

      if (pf) writeV(nb, tid, vs);                  // V drained under softmax

      if (doC) {
        // ---- O += P . V ----
#pragma unroll
        for (int kc = 0; kc < 4; ++kc) {
          const int cb = 32 * kc + 8 * g2;
#pragma unroll
          for (int df = 0; df < 2; ++df) {
            const int row = 32 * df + l31;
            bf16x4 v0 = *(const bf16x4*)(vb + swzV(row, cb));
            bf16x4 v1 = *(const bf16x4*)(vb + swzV(row, cb + 16));
            bf16x8 vf = __builtin_shufflevector(v0, v1, 0, 1, 2, 3, 4, 5, 6, 7);
            if (df == 0)
              acc0 = __builtin_amdgcn_mfma_f32_32x32x16_bf16(pa[kc], vf, acc0, 0, 0, 0);
            else
              acc1 = __builtin_amdgcn_mfma_f32_32x32x16_bf16(pa[kc], vf, acc1, 0, 0, 0);
          }
        }
      }
    }

    // ---- 2-way merge (grp1 -> grp0) via LDS arena, grp0 writes out ----
    __syncthreads();
    float* arena = (float*)&smem[0][0][0];   // 2 slots x 2112 floats
    if (grp == 1) {
      float* ab = arena + st * 2112;
#pragma unroll
      for (int rr = 0; rr < 16; ++rr) {
        int rm = (rr & 3) + ((rr >> 2) << 3) + (g2 << 2);
        ab[rm * 64 + l31]      = acc0[rr];
        ab[rm * 64 + 32 + l31] = acc1[rr];
      }
      if (g2 == 0) { ab[2048 + l31] = m_run; ab[2080 + l31] = l_run; }
    }
    __syncthreads();
    if (grp == 0) {
      const float* ab = arena + st * 2112;
      const float mB = ab[2048 + l31];
      const float lB = ab[2080 + l31];
      const float mN = fmaxf(m_run, mB);
      float fA = __builtin_amdgcn_exp2f(m_run - mN);
      float fB = __builtin_amdgcn_exp2f(mB - mN);
      const float lT = l_run * fA + lB * fB;
      const float linv = 1.0f / lT;
      fA *= linv; fB *= linv;
#pragma unroll
      for (int rr = 0; rr < 16; ++rr) {
        const int rm = (rr & 3) + ((rr >> 2) << 3) + (g2 << 2);
        const float FA = __shfl(fA, rm);
        const float FB = __shfl(fB, rm);
        const float o0 = acc0[rr] * FA + ab[rm * 64 + l31] * FB;
        const float o1 = acc1[rr] * FA + ab[rm * 64 + 32 + l31] * FB;
        const size_t row = (size_t)(qs + rm) * ROWSTR;
        op[row + l31]      = o0;
        op[row + 32 + l31] = o1;
      }
    }
  }
}

}  // namespace

extern "C" void kernel_launch(void* const* d_in, const int* in_sizes, int n_in,
                              void* d_out, int out_size, void* d_ws, size_t ws_size,
                              hipStream_t stream) {
  (void)in_sizes; (void)n_in; (void)out_size; (void)d_ws; (void)ws_size;
  const float* q = (const float*)d_in[0];
  const float* k = (const float*)d_in[1];
  const float* v = (const float*)d_in[2];
  const int* flag = (const int*)d_in[3];
  float* out = (float*)d_out;
  fattn_kernel<<<dim3(512), dim3(256), 0, stream>>>(q, k, v, flag, out);
}

// Round 8
// 56.207 us; speedup vs baseline: 1.6463x; 1.6463x over previous
//
#include <hip/hip_runtime.h>
#include <hip/hip_bf16.h>

namespace {

constexpr int Nn = 2048;
constexpr int Hh = 16;
constexpr int Dd = 64;
constexpr int ROWSTR = Hh * Dd;      // 1024 floats between consecutive tokens
constexpr int KVB = 64;              // KV tile rows
constexpr int NTILES = Nn / KVB;     // 32
constexpr int QB = 128;              // q-rows per block (4 waves x 32)
constexpr int NQT = Nn / QB;         // 16
constexpr size_t IMG_TILE = 16384;   // per KV tile: K-frag image 8KB | V-frag image 8KB
constexpr size_t WS_NEED = (size_t)32 * NTILES * IMG_TILE;   // 16.78 MB

typedef __bf16 bf16x8 __attribute__((ext_vector_type(8)));
typedef __bf16 bf16x4 __attribute__((ext_vector_type(4)));
typedef float  f32x16 __attribute__((ext_vector_type(16)));

// ============================ pre-pass =====================================
// Builds fragment-ordered bf16 tile images in ws:
//   img(bh,T) = ws + (bh*32+T)*16KB
//   K entry  [slot = half*4+dc][lane = l31|(g2<<5)] : bf16x8 =
//       K[T*64 + half*32 + l31][dc*16 + g2*8 .. +7]
//   V entry  [slot = kc*2+df ][lane = l31|(g2<<5)] : bf16x8 =
//       V[T*64 + 16kc + 4g2 + {0,1,2,3,8,9,10,11}][32df + l31]
// Main-loop LDS reads become slot*1024 + lane*16 -> conflict-free b128.
__global__ __launch_bounds__(256, 2) void prep_kernel(
    const float* __restrict__ Kg, const float* __restrict__ Vg,
    char* __restrict__ ws) {
  const int bid = blockIdx.x;
  const int bh  = bid & 31;
  const int T   = bid >> 5;
  const int tid = threadIdx.x;
  const int b = bh >> 4, h = bh & 15;
  const size_t base = ((size_t)b * Nn * Hh + h) * Dd;
  const float* kp = Kg + base;
  const float* vp = Vg + base;
  char* img = ws + (size_t)(bh * NTILES + T) * IMG_TILE;

  // ---- K: thread = (row, seg16) ; coalesced 64B reads along d ----
  {
    const int row = tid >> 2;          // 0..63
    const int seg = tid & 3;           // 16 floats
    const float* kr = kp + (size_t)(T * 64 + row) * ROWSTR + seg * 16;
    float4 f0 = ((const float4*)kr)[0];
    float4 f1 = ((const float4*)kr)[1];
    float4 f2 = ((const float4*)kr)[2];
    float4 f3 = ((const float4*)kr)[3];
    const int half = row >> 5, l31r = row & 31;
    char* slotp = img + (half * 4 + seg) * 1024;
    bf16x8 w0 = { (__bf16)f0.x, (__bf16)f0.y, (__bf16)f0.z, (__bf16)f0.w,
                  (__bf16)f1.x, (__bf16)f1.y, (__bf16)f1.z, (__bf16)f1.w };
    bf16x8 w1 = { (__bf16)f2.x, (__bf16)f2.y, (__bf16)f2.z, (__bf16)f2.w,
                  (__bf16)f3.x, (__bf16)f3.y, (__bf16)f3.z, (__bf16)f3.w };
    *(bf16x8*)(slotp + l31r * 16) = w0;            // g2 = 0 entry
    *(bf16x8*)(slotp + (l31r + 32) * 16) = w1;     // g2 = 1 entry
  }
  // ---- V: thread = 2 entries; scalar loads coalesced along d ----
  char* imgV = img + 8192;
#pragma unroll
  for (int e2 = 0; e2 < 2; ++e2) {
    const int e = e2 * 256 + tid;
    const int slotV = e >> 6, lane = e & 63;
    const int kc = slotV >> 1, df = slotV & 1;
    const int l31e = lane & 31, g2e = lane >> 5;
    const int d = 32 * df + l31e;
    const size_t kv0 = (size_t)(T * 64 + 16 * kc + 4 * g2e);
    const float* vb = vp + d;
    bf16x8 w;
#pragma unroll
    for (int i2 = 0; i2 < 4; ++i2) w[i2]     = (__bf16)vb[(kv0 + i2) * ROWSTR];
#pragma unroll
    for (int i2 = 0; i2 < 4; ++i2) w[4 + i2] = (__bf16)vb[(kv0 + 8 + i2) * ROWSTR];
    *(bf16x8*)(imgV + slotV * 1024 + lane * 16) = w;
  }
}

// ============================ main kernel ==================================
__global__ __launch_bounds__(256, 2) void fattn_kernel(
    const float* __restrict__ Qg, const char* __restrict__ ws,
    const int* __restrict__ flag, float* __restrict__ Og) {
  __shared__ __align__(16) char smem[2][16384];   // dbuf tile image

  const int tid  = threadIdx.x;
  const int lane = tid & 63;
  const int wv   = tid >> 6;   // q-stripe 0..3
  const int l31  = lane & 31;
  const int g2   = lane >> 5;

  // grid 512: half 0 = heavy q-tiles (dispatch first), half 1 = light backfill.
  const int bid  = blockIdx.x;
  const int half = bid >> 8;
  const int r    = bid & 255;
  const int bh   = ((r & 7) << 2) | (r >> 6);   // bid&7 -> 4-head XCD group
  const int ti   = (r >> 3) & 7;
  const int b    = bh >> 4;
  const int h    = bh & 15;
  const int causal = flag[0];
  const int Tq   = half ? ti : (NQT - 1 - ti);

  const size_t base = ((size_t)b * Nn * Hh + h) * Dd;
  const float* qp = Qg + base;
  const char*  img = ws + (size_t)bh * NTILES * IMG_TILE;
  float*       op = Og + base;

  const float SCALE = 0.125f * 1.44269504088896340736f;  // 1/sqrt(64) * log2(e)

  const int qs = Tq * QB + wv * 32;
  const int Tblock = causal ? (2 * Tq + 2) : NTILES;
  const int Twave  = causal ? ((qs + 31) / KVB + 1) : NTILES;

  // ---- Q fragments ----
  bf16x8 qf[4];
#pragma unroll
  for (int dc = 0; dc < 4; ++dc) {
    const float* qrow = qp + (size_t)(qs + l31) * ROWSTR + dc * 16 + g2 * 8;
    float4 a = *(const float4*)qrow;
    float4 c = *(const float4*)(qrow + 4);
    qf[dc][0] = (__bf16)(a.x * SCALE); qf[dc][1] = (__bf16)(a.y * SCALE);
    qf[dc][2] = (__bf16)(a.z * SCALE); qf[dc][3] = (__bf16)(a.w * SCALE);
    qf[dc][4] = (__bf16)(c.x * SCALE); qf[dc][5] = (__bf16)(c.y * SCALE);
    qf[dc][6] = (__bf16)(c.z * SCALE); qf[dc][7] = (__bf16)(c.w * SCALE);
  }

  f32x16 acc0 = {};
  f32x16 acc1 = {};
  float m_run = -INFINITY;
  float l_run = 0.0f;

  // ---- prologue: copy tile-0 image to LDS ----
#pragma unroll
  for (int it = 0; it < 4; ++it) {
    const int idx = it * 256 + tid;
    *(bf16x8*)(&smem[0][0] + idx * 16) = *(const bf16x8*)(img + idx * 16);
  }

  bf16x8 stg[4];
  for (int t = 0; t < Tblock; ++t) {
    __syncthreads();
    const bool pf = (t + 1 < Tblock);
    // T14: issue next tile-image loads; drain hides under compute
    if (pf) {
      const char* src = img + (size_t)(t + 1) * IMG_TILE;
#pragma unroll
      for (int it = 0; it < 4; ++it)
        stg[it] = *(const bf16x8*)(src + (it * 256 + tid) * 16);
    }

    if (t < Twave) {
      const char* kb = &smem[t & 1][0];
      const char* vb = kb + 8192;

      // ---- S^T = K . Q^T (fragment-ordered image: slot*1024 + lane*16) ----
      f32x16 s0 = {}, s1 = {};
      __builtin_amdgcn_s_setprio(1);
#pragma unroll
      for (int dc = 0; dc < 4; ++dc) {
        bf16x8 kf0 = *(const bf16x8*)(kb + (dc)     * 1024 + lane * 16);
        bf16x8 kf1 = *(const bf16x8*)(kb + (4 + dc) * 1024 + lane * 16);
        s0 = __builtin_amdgcn_mfma_f32_32x32x16_bf16(kf0, qf[dc], s0, 0, 0, 0);
        s1 = __builtin_amdgcn_mfma_f32_32x32x16_bf16(kf1, qf[dc], s1, 0, 0, 0);
      }
      __builtin_amdgcn_s_setprio(0);

      // ---- causal mask (wave's diagonal tile only) ----
      if (causal && t == Twave - 1) {
        const int kvb = t * KVB;
        const int qrow = qs + l31;
#pragma unroll
        for (int rr = 0; rr < 16; ++rr) {
          int rm = (rr & 3) + ((rr >> 2) << 3) + (g2 << 2);
          if (kvb + rm > qrow)      s0[rr] = -INFINITY;
          if (kvb + 32 + rm > qrow) s1[rr] = -INFINITY;
        }
      }

      // ---- max: pairwise tree ----
      float p8[8];
#pragma unroll
      for (int e = 0; e < 8; ++e)
        p8[e] = fmaxf(fmaxf(s0[e], s0[e + 8]), fmaxf(s1[e], s1[e + 8]));
      float mt = fmaxf(fmaxf(fmaxf(p8[0], p8[1]), fmaxf(p8[2], p8[3])),
                       fmaxf(fmaxf(p8[4], p8[5]), fmaxf(p8[6], p8[7])));
      mt = fmaxf(mt, __shfl_xor(mt, 32));
      const float mnew = fmaxf(m_run, mt);

      // ---- exp + sum tree ----
#pragma unroll
      for (int rr = 0; rr < 16; ++rr) {
        s0[rr] = __builtin_amdgcn_exp2f(s0[rr] - mnew);
        s1[rr] = __builtin_amdgcn_exp2f(s1[rr] - mnew);
      }
      float q8[8];
#pragma unroll
      for (int e = 0; e < 8; ++e)
        q8[e] = (s0[e] + s0[e + 8]) + (s1[e] + s1[e + 8]);
      float rs = ((q8[0] + q8[1]) + (q8[2] + q8[3])) +
                 ((q8[4] + q8[5]) + (q8[6] + q8[7]));
      rs += __shfl_xor(rs, 32);
      if (__all(mt <= m_run)) {
        l_run += rs;
      } else {
        const float alpha = __builtin_amdgcn_exp2f(m_run - mnew);
#pragma unroll
        for (int rr = 0; rr < 16; ++rr) {
          float at = __shfl(alpha, (rr & 3) + ((rr >> 2) << 3) + (g2 << 2));
          acc0[rr] *= at;
          acc1[rr] *= at;
        }
        l_run = l_run * alpha + rs;
        m_run = mnew;
      }

      // ---- P fragments (split-4 k-slot pass-through) ----
      bf16x8 pa[4];
#pragma unroll
      for (int kc = 0; kc < 4; ++kc) {
        const f32x16& sv = (kc < 2) ? s0 : s1;
        const int rbase = (kc & 1) * 8;
#pragma unroll
        for (int jj = 0; jj < 8; ++jj) pa[kc][jj] = (__bf16)sv[rbase + jj];
      }

      // ---- O += P . V  (V image: one b128 per fragment) ----
      __builtin_amdgcn_s_setprio(1);
#pragma unroll
      for (int kc = 0; kc < 4; ++kc) {
#pragma unroll
        for (int df = 0; df < 2; ++df) {
          bf16x8 vf = *(const bf16x8*)(vb + (kc * 2 + df) * 1024 + lane * 16);
          if (df == 0)
            acc0 = __builtin_amdgcn_mfma_f32_32x32x16_bf16(pa[kc], vf, acc0, 0, 0, 0);
          else
            acc1 = __builtin_amdgcn_mfma_f32_32x32x16_bf16(pa[kc], vf, acc1, 0, 0, 0);
        }
      }
      __builtin_amdgcn_s_setprio(0);
    }

    // write next tile image into the other buffer (prev readers done at sync)
    if (pf) {
      char* dst = &smem[(t + 1) & 1][0];
#pragma unroll
      for (int it = 0; it < 4; ++it)
        *(bf16x8*)(dst + (it * 256 + tid) * 16) = stg[it];
    }
  }

  // ---- epilogue ----
  const float linv = 1.0f / l_run;
#pragma unroll
  for (int rr = 0; rr < 16; ++rr) {
    const int rm = (rr & 3) + ((rr >> 2) << 3) + (g2 << 2);
    const float li = __shfl(linv, rm);
    const size_t row = (size_t)(qs + rm) * ROWSTR;
    op[row + l31]      = acc0[rr] * li;
    op[row + 32 + l31] = acc1[rr] * li;
  }
}

// ==================== fallback (self-contained, R6-proven) ==================
__device__ __forceinline__ int swzK(int row, int colByte) {
  return (row * 128 + colByte) ^ ((row & 7) << 4);
}
__device__ __forceinline__ int swzV(int row, int colByte) {
  return (row * 128 + colByte) ^ (((row & 7) << 4) | (((row >> 3) & 1) << 3));
}
struct SR { float4 k[4]; float v[16]; };
__device__ __forceinline__ void fb_issue(const float* kp, const float* vp,
                                         int kv0, int tid, SR& s) {
#pragma unroll
  for (int it = 0; it < 4; ++it) {
    int idx = it * 256 + tid;
    int kvr = idx >> 4, c4 = idx & 15;
    s.k[it] = *(const float4*)(kp + (size_t)(kv0 + kvr) * ROWSTR + c4 * 4);
  }
#pragma unroll
  for (int it = 0; it < 4; ++it) {
    int idx = it * 256 + tid;
    int d8 = idx & 63, kv4 = idx >> 6;
#pragma unroll
    for (int i2 = 0; i2 < 4; ++i2)
      s.v[it * 4 + i2] = vp[(size_t)(kv0 + kv4 * 4 + i2) * ROWSTR + d8];
  }
}
__device__ __forceinline__ void fb_write(char* kb, char* vb, int tid, const SR& s) {
#pragma unroll
  for (int it = 0; it < 4; ++it) {
    int idx = it * 256 + tid;
    int kvr = idx >> 4, c4 = idx & 15;
    bf16x4 w = { (__bf16)s.k[it].x, (__bf16)s.k[it].y,
                 (__bf16)s.k[it].z, (__bf16)s.k[it].w };
    *(bf16x4*)(kb + swzK(kvr, c4 * 8)) = w;
  }
#pragma unroll
  for (int it = 0; it < 4; ++it) {
    int idx = it * 256 + tid;
    int d8 = idx & 63, kv4 = idx >> 6;
    bf16x4 w = { (__bf16)s.v[it * 4 + 0], (__bf16)s.v[it * 4 + 1],
                 (__bf16)s.v[it * 4 + 2], (__bf16)s.v[it * 4 + 3] };
    *(bf16x4*)(vb + swzV(d8, kv4 * 8)) = w;
  }
}
__global__ __launch_bounds__(256, 2) void fattn_fb(
    const float* __restrict__ Qg, const float* __restrict__ Kg,
    const float* __restrict__ Vg, const int* __restrict__ flag,
    float* __restrict__ Og) {
  __shared__ __align__(16) char smem[16384];
  const int tid  = threadIdx.x;
  const int lane = tid & 63;
  const int wv   = tid >> 6;
  const int l31  = lane & 31;
  const int g2   = lane >> 5;
  const int bid = blockIdx.x;
  const int pidx = bid >> 1;
  const int side = bid & 1;
  const int bh  = ((pidx & 7) << 2) | (pidx >> 6);
  const int ti  = (pidx >> 3) & 7;
  const int b   = bh >> 4;
  const int h   = bh & 15;
  const int causal = flag[0];
  const int Tq  = side ? ti : (NQT - 1 - ti);
  const size_t base = ((size_t)b * Nn * Hh + h) * Dd;
  const float* qp = Qg + base;
  const float* kp = Kg + base;
  const float* vp = Vg + base;
  float*       op = Og + base;
  const float SCALE = 0.125f * 1.44269504088896340736f;
  const int qs = Tq * QB + wv * 32;
  const int Tblock = causal ? (2 * Tq + 2) : NTILES;
  const int Twave  = causal ? ((qs + 31) / KVB + 1) : NTILES;
  bf16x8 qf[4];
#pragma unroll
  for (int dc = 0; dc < 4; ++dc) {
    const float* qrow = qp + (size_t)(qs + l31) * ROWSTR + dc * 16 + g2 * 8;
    float4 a = *(const float4*)qrow;
    float4 c = *(const float4*)(qrow + 4);
    qf[dc][0] = (__bf16)(a.x * SCALE); qf[dc][1] = (__bf16)(a.y * SCALE);
    qf[dc][2] = (__bf16)(a.z * SCALE); qf[dc][3] = (__bf16)(a.w * SCALE);
    qf[dc][4] = (__bf16)(c.x * SCALE); qf[dc][5] = (__bf16)(c.y * SCALE);
    qf[dc][6] = (__bf16)(c.z * SCALE); qf[dc][7] = (__bf16)(c.w * SCALE);
  }
  f32x16 acc0 = {}, acc1 = {};
  float m_run = -INFINITY, l_run = 0.0f;
  SR st;
  fb_issue(kp, vp, 0, tid, st);
  fb_write(smem, smem + 8192, tid, st);
  for (int t = 0; t < Tblock; ++t) {
    __syncthreads();
    const bool pf = (t + 1 < Tblock);
    if (pf) fb_issue(kp, vp, (t + 1) * KVB, tid, st);
    if (t < Twave) {
      const char* kb = smem;
      const char* vb = smem + 8192;
      f32x16 s0 = {}, s1 = {};
#pragma unroll
      for (int dc = 0; dc < 4; ++dc) {
        bf16x8 kf0 = *(const bf16x8*)(kb + swzK(l31,      32 * dc + 16 * g2));
        bf16x8 kf1 = *(const bf16x8*)(kb + swzK(32 + l31, 32 * dc + 16 * g2));
        s0 = __builtin_amdgcn_mfma_f32_32x32x16_bf16(kf0, qf[dc], s0, 0, 0, 0);
        s1 = __builtin_amdgcn_mfma_f32_32x32x16_bf16(kf1, qf[dc], s1, 0, 0, 0);
      }
      if (causal && t == Twave - 1) {
        const int kvb = t * KVB;
        const int qrow = qs + l31;
#pragma unroll
        for (int rr = 0; rr < 16; ++rr) {
          int rm = (rr & 3) + ((rr >> 2) << 3) + (g2 << 2);
          if (kvb + rm > qrow)      s0[rr] = -INFINITY;
          if (kvb + 32 + rm > qrow) s1[rr] = -INFINITY;
        }
      }
      float p8[8];
#pragma unroll
      for (int e = 0; e < 8; ++e)
        p8[e] = fmaxf(fmaxf(s0[e], s0[e + 8]), fmaxf(s1[e], s1[e + 8]));
      float mt = fmaxf(fmaxf(fmaxf(p8[0], p8[1]), fmaxf(p8[2], p8[3])),
                       fmaxf(fmaxf(p8[4], p8[5]), fmaxf(p8[6], p8[7])));
      mt = fmaxf(mt, __shfl_xor(mt, 32));
      const float mnew = fmaxf(m_run, mt);
#pragma unroll
      for (int rr = 0; rr < 16; ++rr) {
        s0[rr] = __builtin_amdgcn_exp2f(s0[rr] - mnew);
        s1[rr] = __builtin_amdgcn_exp2f(s1[rr] - mnew);
      }
      float q8[8];
#pragma unroll
      for (int e = 0; e < 8; ++e)
        q8[e] = (s0[e] + s0[e + 8]) + (s1[e] + s1[e + 8]);
      float rs = ((q8[0] + q8[1]) + (q8[2] + q8[3])) +
                 ((q8[4] + q8[5]) + (q8[6] + q8[7]));
      rs += __shfl_xor(rs, 32);
      if (__all(mt <= m_run)) {
        l_run += rs;
      } else {
        const float alpha = __builtin_amdgcn_exp2f(m_run - mnew);
#pragma unroll
        for (int rr = 0; rr < 16; ++rr) {
          float at = __shfl(alpha, (rr & 3) + ((rr >> 2) << 3) + (g2 << 2));
          acc0[rr] *= at;
          acc1[rr] *= at;
        }
        l_run = l_run * alpha + rs;
        m_run = mnew;
      }
      bf16x8 pa[4];
#pragma unroll
      for (int kc = 0; kc < 4; ++kc) {
        const f32x16& sv = (kc < 2) ? s0 : s1;
        const int rbase = (kc & 1) * 8;
#pragma unroll
        for (int jj = 0; jj < 8; ++jj) pa[kc][jj] = (__bf16)sv[rbase + jj];
      }
#pragma unroll
      for (int kc = 0; kc < 4; ++kc) {
        const int cb = 32 * kc + 8 * g2;
#pragma unroll
        for (int df = 0; df < 2; ++df) {
          const int row = 32 * df + l31;
          bf16x4 v0 = *(const bf16x4*)(vb + swzV(row, cb));
          bf16x4 v1 = *(const bf16x4*)(vb + swzV(row, cb + 16));
          bf16x8 vf = __builtin_shufflevector(v0, v1, 0, 1, 2, 3, 4, 5, 6, 7);
          if (df == 0)
            acc0 = __builtin_amdgcn_mfma_f32_32x32x16_bf16(pa[kc], vf, acc0, 0, 0, 0);
          else
            acc1 = __builtin_amdgcn_mfma_f32_32x32x16_bf16(pa[kc], vf, acc1, 0, 0, 0);
        }
      }
    }
    __syncthreads();
    if (pf) fb_write(smem, smem + 8192, tid, st);
  }
  const float linv = 1.0f / l_run;
#pragma unroll
  for (int rr = 0; rr < 16; ++rr) {
    const int rm = (rr & 3) + ((rr >> 2) << 3) + (g2 << 2);
    const float li = __shfl(linv, rm);
    const size_t row = (size_t)(qs + rm) * ROWSTR;
    op[row + l31]      = acc0[rr] * li;
    op[row + 32 + l31] = acc1[rr] * li;
  }
}

}  // namespace

extern "C" void kernel_launch(void* const* d_in, const int* in_sizes, int n_in,
                              void* d_out, int out_size, void* d_ws, size_t ws_size,
                              hipStream_t stream) {
  (void)in_sizes; (void)n_in; (void)out_size;
  const float* q = (const float*)d_in[0];
  const float* k = (const float*)d_in[1];
  const float* v = (const float*)d_in[2];
  const int* flag = (const int*)d_in[3];
  float* out = (float*)d_out;
  if (ws_size >= WS_NEED) {
    char* ws = (char*)d_ws;
    prep_kernel<<<dim3(1024), dim3(256), 0, stream>>>(k, v, ws);
    fattn_kernel<<<dim3(512), dim3(256), 0, stream>>>(q, ws, flag, out);
  } else {
    fattn_fb<<<dim3(512), dim3(256), 0, stream>>>(q, k, v, flag, out);
  }
}

// Round 9
// 51.160 us; speedup vs baseline: 1.8087x; 1.0986x over previous
//
#include <hip/hip_runtime.h>
#include <hip/hip_bf16.h>

namespace {

constexpr int Nn = 2048;
constexpr int Hh = 16;
constexpr int Dd = 64;
constexpr int ROWSTR = Hh * Dd;      // 1024 floats between consecutive tokens
constexpr int KVB = 64;              // KV tile rows
constexpr int NTILES = Nn / KVB;     // 32
constexpr size_t IMG_TILE = 16384;   // per KV tile: K-frag image 8KB | V-frag image 8KB
constexpr size_t WS_NEED = (size_t)32 * NTILES * IMG_TILE;   // 16.78 MB

typedef __bf16 bf16x8 __attribute__((ext_vector_type(8)));
typedef __bf16 bf16x4 __attribute__((ext_vector_type(4)));
typedef float  f32x16 __attribute__((ext_vector_type(16)));

// ============================ pre-pass =====================================
// Builds fragment-ordered bf16 tile images in ws (unchanged from R8):
//   img(bh,T) = ws + (bh*32+T)*16KB
//   K entry [slot = half*4+dc][lane] ; V entry [slot = kc*2+df][lane]
// Main-loop LDS reads are slot*1024 + lane*16 -> conflict-free b128.
__global__ __launch_bounds__(256, 2) void prep_kernel(
    const float* __restrict__ Kg, const float* __restrict__ Vg,
    char* __restrict__ ws) {
  const int bid = blockIdx.x;
  const int bh  = bid & 31;
  const int T   = bid >> 5;
  const int tid = threadIdx.x;
  const int b = bh >> 4, h = bh & 15;
  const size_t base = ((size_t)b * Nn * Hh + h) * Dd;
  const float* kp = Kg + base;
  const float* vp = Vg + base;
  char* img = ws + (size_t)(bh * NTILES + T) * IMG_TILE;

  // ---- K: thread = (row, seg16) ; coalesced 64B reads along d ----
  {
    const int row = tid >> 2;          // 0..63
    const int seg = tid & 3;           // 16 floats
    const float* kr = kp + (size_t)(T * 64 + row) * ROWSTR + seg * 16;
    float4 f0 = ((const float4*)kr)[0];
    float4 f1 = ((const float4*)kr)[1];
    float4 f2 = ((const float4*)kr)[2];
    float4 f3 = ((const float4*)kr)[3];
    const int half = row >> 5, l31r = row & 31;
    char* slotp = img + (half * 4 + seg) * 1024;
    bf16x8 w0 = { (__bf16)f0.x, (__bf16)f0.y, (__bf16)f0.z, (__bf16)f0.w,
                  (__bf16)f1.x, (__bf16)f1.y, (__bf16)f1.z, (__bf16)f1.w };
    bf16x8 w1 = { (__bf16)f2.x, (__bf16)f2.y, (__bf16)f2.z, (__bf16)f2.w,
                  (__bf16)f3.x, (__bf16)f3.y, (__bf16)f3.z, (__bf16)f3.w };
    *(bf16x8*)(slotp + l31r * 16) = w0;            // g2 = 0 entry
    *(bf16x8*)(slotp + (l31r + 32) * 16) = w1;     // g2 = 1 entry
  }
  // ---- V: thread = 2 entries; scalar loads coalesced along d ----
  char* imgV = img + 8192;
#pragma unroll
  for (int e2 = 0; e2 < 2; ++e2) {
    const int e = e2 * 256 + tid;
    const int slotV = e >> 6, lane = e & 63;
    const int kc = slotV >> 1, df = slotV & 1;
    const int l31e = lane & 31, g2e = lane >> 5;
    const int d = 32 * df + l31e;
    const size_t kv0 = (size_t)(T * 64 + 16 * kc + 4 * g2e);
    const float* vb = vp + d;
    bf16x8 w;
#pragma unroll
    for (int i2 = 0; i2 < 4; ++i2) w[i2]     = (__bf16)vb[(kv0 + i2) * ROWSTR];
#pragma unroll
    for (int i2 = 0; i2 < 4; ++i2) w[4 + i2] = (__bf16)vb[(kv0 + 8 + i2) * ROWSTR];
    *(bf16x8*)(imgV + slotV * 1024 + lane * 16) = w;
  }
}

// ============================ main kernel ==================================
// 512 UNIFORM blocks: block = (bh, pair j) handles q-tiles {31-j, j} (QB=64)
// sequentially; 4 waves = 2 q-stripes x 2 KV-parity groups; in-LDS merge.
// Every block = 17 intervals -> flat 2 blocks/CU (8 waves) whole runtime.
__global__ __launch_bounds__(256, 2) void fattn_kernel(
    const float* __restrict__ Qg, const char* __restrict__ ws,
    const int* __restrict__ flag, float* __restrict__ Og) {
  __shared__ __align__(16) char smem[2][2][16384];   // [buf][parity]

  const int tid  = threadIdx.x;
  const int lane = tid & 63;
  const int wv   = tid >> 6;   // 0..3
  const int grp  = wv >> 1;    // KV parity: tiles 2i+grp
  const int st   = wv & 1;     // q stripe (32 rows) within the 64-row q-tile
  const int l31  = lane & 31;
  const int g2   = lane >> 5;

  const int bid = blockIdx.x;
  const int bh  = ((bid & 7) << 2) | ((bid >> 3) & 3);  // bid&7 -> 4-head XCD group
  const int j   = bid >> 5;                             // 0..15
  const int b   = bh >> 4;
  const int h   = bh & 15;
  const int causal = flag[0];

  const size_t base = ((size_t)b * Nn * Hh + h) * Dd;
  const float* qp = Qg + base;
  const char*  img = ws + (size_t)bh * NTILES * IMG_TILE;
  float*       op = Og + base;

  const float SCALE = 0.125f * 1.44269504088896340736f;  // 1/sqrt(64) * log2(e)

  for (int pass = 0; pass < 2; ++pass) {
    const int Tq = pass ? j : (31 - j);        // q-tile of 64 rows
    const int qs = Tq * 64 + st * 32;          // wave's first q row
    const int NI = causal ? ((Tq + 2) >> 1) : (NTILES / 2);   // tile-pair intervals
    const int nC = causal ? ((Tq >= grp) ? (((Tq - grp) >> 1) + 1) : 0)
                          : (NTILES / 2);      // tiles computed by this parity

    __syncthreads();   // previous pass's merge-arena reads complete

    // ---- Q fragments (contiguous k-slot map) ----
    bf16x8 qf[4];
#pragma unroll
    for (int dc = 0; dc < 4; ++dc) {
      const float* qrow = qp + (size_t)(qs + l31) * ROWSTR + dc * 16 + g2 * 8;
      float4 a = *(const float4*)qrow;
      float4 c = *(const float4*)(qrow + 4);
      qf[dc][0] = (__bf16)(a.x * SCALE); qf[dc][1] = (__bf16)(a.y * SCALE);
      qf[dc][2] = (__bf16)(a.z * SCALE); qf[dc][3] = (__bf16)(a.w * SCALE);
      qf[dc][4] = (__bf16)(c.x * SCALE); qf[dc][5] = (__bf16)(c.y * SCALE);
      qf[dc][6] = (__bf16)(c.z * SCALE); qf[dc][7] = (__bf16)(c.w * SCALE);
    }

    f32x16 acc0 = {};   // O cols 0..31 (col = l31)
    f32x16 acc1 = {};   // O cols 32..63
    float m_run = -INFINITY;
    float l_run = 0.0f;

    // ---- prologue: copy tile images {0,1} into buf 0 ----
    {
      bf16x8 stg[8];
#pragma unroll
      for (int it = 0; it < 8; ++it)
        stg[it] = *(const bf16x8*)(img + (it * 256 + tid) * 16);
#pragma unroll
      for (int it = 0; it < 8; ++it)
        *(bf16x8*)(&smem[0][it >> 2][0] + ((it & 3) * 256 + tid) * 16) = stg[it];
    }

    for (int i = 0; i < NI; ++i) {
      __syncthreads();
      const bool pf = (i + 1 < NI);
      bf16x8 stg[8];
      // T14: issue next pair's image loads; drain hides under compute
      if (pf) {
        const char* src = img + (size_t)(2 * i + 2) * IMG_TILE;
#pragma unroll
        for (int it = 0; it < 8; ++it)
          stg[it] = *(const bf16x8*)(src + (it * 256 + tid) * 16);
      }

      if (i < nC) {
        const char* kb = &smem[i & 1][grp][0];
        const char* vb = kb + 8192;

        // ---- S^T = K . Q^T (image: slot*1024 + lane*16, conflict-free) ----
        f32x16 s0 = {}, s1 = {};
        __builtin_amdgcn_s_setprio(1);
#pragma unroll
        for (int dc = 0; dc < 4; ++dc) {
          bf16x8 kf0 = *(const bf16x8*)(kb + (dc)     * 1024 + lane * 16);
          bf16x8 kf1 = *(const bf16x8*)(kb + (4 + dc) * 1024 + lane * 16);
          s0 = __builtin_amdgcn_mfma_f32_32x32x16_bf16(kf0, qf[dc], s0, 0, 0, 0);
          s1 = __builtin_amdgcn_mfma_f32_32x32x16_bf16(kf1, qf[dc], s1, 0, 0, 0);
        }
        __builtin_amdgcn_s_setprio(0);

        // ---- causal mask (this parity's diagonal tile only) ----
        if (causal && (2 * i + grp) == Tq) {
          const int kvb = Tq * KVB;
          const int qrow = qs + l31;
#pragma unroll
          for (int rr = 0; rr < 16; ++rr) {
            int rm = (rr & 3) + ((rr >> 2) << 3) + (g2 << 2);
            if (kvb + rm > qrow)      s0[rr] = -INFINITY;
            if (kvb + 32 + rm > qrow) s1[rr] = -INFINITY;
          }
        }

        // ---- max: pairwise tree ----
        float p8[8];
#pragma unroll
        for (int e = 0; e < 8; ++e)
          p8[e] = fmaxf(fmaxf(s0[e], s0[e + 8]), fmaxf(s1[e], s1[e + 8]));
        float mt = fmaxf(fmaxf(fmaxf(p8[0], p8[1]), fmaxf(p8[2], p8[3])),
                         fmaxf(fmaxf(p8[4], p8[5]), fmaxf(p8[6], p8[7])));
        mt = fmaxf(mt, __shfl_xor(mt, 32));
        const float mnew = fmaxf(m_run, mt);

        // ---- exp + sum tree ----
#pragma unroll
        for (int rr = 0; rr < 16; ++rr) {
          s0[rr] = __builtin_amdgcn_exp2f(s0[rr] - mnew);
          s1[rr] = __builtin_amdgcn_exp2f(s1[rr] - mnew);
        }
        float q8[8];
#pragma unroll
        for (int e = 0; e < 8; ++e)
          q8[e] = (s0[e] + s0[e + 8]) + (s1[e] + s1[e + 8]);
        float rs = ((q8[0] + q8[1]) + (q8[2] + q8[3])) +
                   ((q8[4] + q8[5]) + (q8[6] + q8[7]));
        rs += __shfl_xor(rs, 32);
        if (__all(mt <= m_run)) {
          l_run += rs;
        } else {
          const float alpha = __builtin_amdgcn_exp2f(m_run - mnew);
#pragma unroll
          for (int rr = 0; rr < 16; ++rr) {
            float at = __shfl(alpha, (rr & 3) + ((rr >> 2) << 3) + (g2 << 2));
            acc0[rr] *= at;
            acc1[rr] *= at;
          }
          l_run = l_run * alpha + rs;
          m_run = mnew;
        }

        // ---- P fragments (split-4 k-slot pass-through) ----
        bf16x8 pa[4];
#pragma unroll
        for (int kc = 0; kc < 4; ++kc) {
          const f32x16& sv = (kc < 2) ? s0 : s1;
          const int rbase = (kc & 1) * 8;
#pragma unroll
          for (int jj = 0; jj < 8; ++jj) pa[kc][jj] = (__bf16)sv[rbase + jj];
        }

        // ---- O += P . V (V image: one b128 per fragment) ----
        __builtin_amdgcn_s_setprio(1);
#pragma unroll
        for (int kc = 0; kc < 4; ++kc) {
#pragma unroll
          for (int df = 0; df < 2; ++df) {
            bf16x8 vf = *(const bf16x8*)(vb + (kc * 2 + df) * 1024 + lane * 16);
            if (df == 0)
              acc0 = __builtin_amdgcn_mfma_f32_32x32x16_bf16(pa[kc], vf, acc0, 0, 0, 0);
            else
              acc1 = __builtin_amdgcn_mfma_f32_32x32x16_bf16(pa[kc], vf, acc1, 0, 0, 0);
          }
        }
        __builtin_amdgcn_s_setprio(0);
      }

      // write next pair's images into the other buffer
      if (pf) {
#pragma unroll
        for (int it = 0; it < 8; ++it)
          *(bf16x8*)(&smem[(i + 1) & 1][it >> 2][0] +
                     ((it & 3) * 256 + tid) * 16) = stg[it];
      }
    }

    // ---- 2-way merge (grp1 -> grp0) via LDS arena, grp0 writes out ----
    __syncthreads();
    float* arena = (float*)&smem[0][0][0];   // 2 slots x 2112 floats
    if (grp == 1) {
      float* ab = arena + st * 2112;
#pragma unroll
      for (int rr = 0; rr < 16; ++rr) {
        int rm = (rr & 3) + ((rr >> 2) << 3) + (g2 << 2);
        ab[rm * 64 + l31]      = acc0[rr];
        ab[rm * 64 + 32 + l31] = acc1[rr];
      }
      if (g2 == 0) { ab[2048 + l31] = m_run; ab[2080 + l31] = l_run; }
    }
    __syncthreads();
    if (grp == 0) {
      const float* ab = arena + st * 2112;
      const float mB = ab[2048 + l31];
      const float lB = ab[2080 + l31];
      const float mN = fmaxf(m_run, mB);
      float fA = __builtin_amdgcn_exp2f(m_run - mN);
      float fB = __builtin_amdgcn_exp2f(mB - mN);
      const float lT = l_run * fA + lB * fB;
      const float linv = 1.0f / lT;
      fA *= linv; fB *= linv;
#pragma unroll
      for (int rr = 0; rr < 16; ++rr) {
        const int rm = (rr & 3) + ((rr >> 2) << 3) + (g2 << 2);
        const float FA = __shfl(fA, rm);
        const float FB = __shfl(fB, rm);
        const float o0 = acc0[rr] * FA + ab[rm * 64 + l31] * FB;
        const float o1 = acc1[rr] * FA + ab[rm * 64 + 32 + l31] * FB;
        const size_t row = (size_t)(qs + rm) * ROWSTR;
        op[row + l31]      = o0;
        op[row + 32 + l31] = o1;
      }
    }
  }
}

// ==================== fallback (self-contained, R6-proven) ==================
__device__ __forceinline__ int swzK(int row, int colByte) {
  return (row * 128 + colByte) ^ ((row & 7) << 4);
}
__device__ __forceinline__ int swzV(int row, int colByte) {
  return (row * 128 + colByte) ^ (((row & 7) << 4) | (((row >> 3) & 1) << 3));
}
struct SR { float4 k[4]; float v[16]; };
__device__ __forceinline__ void fb_issue(const float* kp, const float* vp,
                                         int kv0, int tid, SR& s) {
#pragma unroll
  for (int it = 0; it < 4; ++it) {
    int idx = it * 256 + tid;
    int kvr = idx >> 4, c4 = idx & 15;
    s.k[it] = *(const float4*)(kp + (size_t)(kv0 + kvr) * ROWSTR + c4 * 4);
  }
#pragma unroll
  for (int it = 0; it < 4; ++it) {
    int idx = it * 256 + tid;
    int d8 = idx & 63, kv4 = idx >> 6;
#pragma unroll
    for (int i2 = 0; i2 < 4; ++i2)
      s.v[it * 4 + i2] = vp[(size_t)(kv0 + kv4 * 4 + i2) * ROWSTR + d8];
  }
}
__device__ __forceinline__ void fb_write(char* kb, char* vb, int tid, const SR& s) {
#pragma unroll
  for (int it = 0; it < 4; ++it) {
    int idx = it * 256 + tid;
    int kvr = idx >> 4, c4 = idx & 15;
    bf16x4 w = { (__bf16)s.k[it].x, (__bf16)s.k[it].y,
                 (__bf16)s.k[it].z, (__bf16)s.k[it].w };
    *(bf16x4*)(kb + swzK(kvr, c4 * 8)) = w;
  }
#pragma unroll
  for (int it = 0; it < 4; ++it) {
    int idx = it * 256 + tid;
    int d8 = idx & 63, kv4 = idx >> 6;
    bf16x4 w = { (__bf16)s.v[it * 4 + 0], (__bf16)s.v[it * 4 + 1],
                 (__bf16)s.v[it * 4 + 2], (__bf16)s.v[it * 4 + 3] };
    *(bf16x4*)(vb + swzV(d8, kv4 * 8)) = w;
  }
}
__global__ __launch_bounds__(256, 2) void fattn_fb(
    const float* __restrict__ Qg, const float* __restrict__ Kg,
    const float* __restrict__ Vg, const int* __restrict__ flag,
    float* __restrict__ Og) {
  __shared__ __align__(16) char smem[16384];
  const int tid  = threadIdx.x;
  const int lane = tid & 63;
  const int wv   = tid >> 6;
  const int l31  = lane & 31;
  const int g2   = lane >> 5;
  const int bid = blockIdx.x;
  const int pidx = bid >> 1;
  const int side = bid & 1;
  const int bh  = ((pidx & 7) << 2) | (pidx >> 6);
  const int ti  = (pidx >> 3) & 7;
  const int b   = bh >> 4;
  const int h   = bh & 15;
  const int causal = flag[0];
  const int Tq  = side ? ti : (15 - ti);
  const size_t base = ((size_t)b * Nn * Hh + h) * Dd;
  const float* qp = Qg + base;
  const float* kp = Kg + base;
  const float* vp = Vg + base;
  float*       op = Og + base;
  const float SCALE = 0.125f * 1.44269504088896340736f;
  const int qs = Tq * 128 + wv * 32;
  const int Tblock = causal ? (2 * Tq + 2) : NTILES;
  const int Twave  = causal ? ((qs + 31) / KVB + 1) : NTILES;
  bf16x8 qf[4];
#pragma unroll
  for (int dc = 0; dc < 4; ++dc) {
    const float* qrow = qp + (size_t)(qs + l31) * ROWSTR + dc * 16 + g2 * 8;
    float4 a = *(const float4*)qrow;
    float4 c = *(const float4*)(qrow + 4);
    qf[dc][0] = (__bf16)(a.x * SCALE); qf[dc][1] = (__bf16)(a.y * SCALE);
    qf[dc][2] = (__bf16)(a.z * SCALE); qf[dc][3] = (__bf16)(a.w * SCALE);
    qf[dc][4] = (__bf16)(c.x * SCALE); qf[dc][5] = (__bf16)(c.y * SCALE);
    qf[dc][6] = (__bf16)(c.z * SCALE); qf[dc][7] = (__bf16)(c.w * SCALE);
  }
  f32x16 acc0 = {}, acc1 = {};
  float m_run = -INFINITY, l_run = 0.0f;
  SR st;
  fb_issue(kp, vp, 0, tid, st);
  fb_write(smem, smem + 8192, tid, st);
  for (int t = 0; t < Tblock; ++t) {
    __syncthreads();
    const bool pf = (t + 1 < Tblock);
    if (pf) fb_issue(kp, vp, (t + 1) * KVB, tid, st);
    if (t < Twave) {
      const char* kb = smem;
      const char* vb = smem + 8192;
      f32x16 s0 = {}, s1 = {};
#pragma unroll
      for (int dc = 0; dc < 4; ++dc) {
        bf16x8 kf0 = *(const bf16x8*)(kb + swzK(l31,      32 * dc + 16 * g2));
        bf16x8 kf1 = *(const bf16x8*)(kb + swzK(32 + l31, 32 * dc + 16 * g2));
        s0 = __builtin_amdgcn_mfma_f32_32x32x16_bf16(kf0, qf[dc], s0, 0, 0, 0);
        s1 = __builtin_amdgcn_mfma_f32_32x32x16_bf16(kf1, qf[dc], s1, 0, 0, 0);
      }
      if (causal && t == Twave - 1) {
        const int kvb = t * KVB;
        const int qrow = qs + l31;
#pragma unroll
        for (int rr = 0; rr < 16; ++rr) {
          int rm = (rr & 3) + ((rr >> 2) << 3) + (g2 << 2);
          if (kvb + rm > qrow)      s0[rr] = -INFINITY;
          if (kvb + 32 + rm > qrow) s1[rr] = -INFINITY;
        }
      }
      float p8[8];
#pragma unroll
      for (int e = 0; e < 8; ++e)
        p8[e] = fmaxf(fmaxf(s0[e], s0[e + 8]), fmaxf(s1[e], s1[e + 8]));
      float mt = fmaxf(fmaxf(fmaxf(p8[0], p8[1]), fmaxf(p8[2], p8[3])),
                       fmaxf(fmaxf(p8[4], p8[5]), fmaxf(p8[6], p8[7])));
      mt = fmaxf(mt, __shfl_xor(mt, 32));
      const float mnew = fmaxf(m_run, mt);
#pragma unroll
      for (int rr = 0; rr < 16; ++rr) {
        s0[rr] = __builtin_amdgcn_exp2f(s0[rr] - mnew);
        s1[rr] = __builtin_amdgcn_exp2f(s1[rr] - mnew);
      }
      float q8[8];
#pragma unroll
      for (int e = 0; e < 8; ++e)
        q8[e] = (s0[e] + s0[e + 8]) + (s1[e] + s1[e + 8]);
      float rs = ((q8[0] + q8[1]) + (q8[2] + q8[3])) +
                 ((q8[4] + q8[5]) + (q8[6] + q8[7]));
      rs += __shfl_xor(rs, 32);
      if (__all(mt <= m_run)) {
        l_run += rs;
      } else {
        const float alpha = __builtin_amdgcn_exp2f(m_run - mnew);
#pragma unroll
        for (int rr = 0; rr < 16; ++rr) {
          float at = __shfl(alpha, (rr & 3) + ((rr >> 2) << 3) + (g2 << 2));
          acc0[rr] *= at;
          acc1[rr] *= at;
        }
        l_run = l_run * alpha + rs;
        m_run = mnew;
      }
      bf16x8 pa[4];
#pragma unroll
      for (int kc = 0; kc < 4; ++kc) {
        const f32x16& sv = (kc < 2) ? s0 : s1;
        const int rbase = (kc & 1) * 8;
#pragma unroll
        for (int jj = 0; jj < 8; ++jj) pa[kc][jj] = (__bf16)sv[rbase + jj];
      }
#pragma unroll
      for (int kc = 0; kc < 4; ++kc) {
        const int cb = 32 * kc + 8 * g2;
#pragma unroll
        for (int df = 0; df < 2; ++df) {
          const int row = 32 * df + l31;
          bf16x4 v0 = *(const bf16x4*)(vb + swzV(row, cb));
          bf16x4 v1 = *(const bf16x4*)(vb + swzV(row, cb + 16));
          bf16x8 vf = __builtin_shufflevector(v0, v1, 0, 1, 2, 3, 4, 5, 6, 7);
          if (df == 0)
            acc0 = __builtin_amdgcn_mfma_f32_32x32x16_bf16(pa[kc], vf, acc0, 0, 0, 0);
          else
            acc1 = __builtin_amdgcn_mfma_f32_32x32x16_bf16(pa[kc], vf, acc1, 0, 0, 0);
        }
      }
    }
    __syncthreads();
    if (pf) fb_write(smem, smem + 8192, tid, st);
  }
  const float linv = 1.0f / l_run;
#pragma unroll
  for (int rr = 0; rr < 16; ++rr) {
    const int rm = (rr & 3) + ((rr >> 2) << 3) + (g2 << 2);
    const float li = __shfl(linv, rm);
    const size_t row = (size_t)(qs + rm) * ROWSTR;
    op[row + l31]      = acc0[rr] * li;
    op[row + 32 + l31] = acc1[rr] * li;
  }
}

}  // namespace

extern "C" void kernel_launch(void* const* d_in, const int* in_sizes, int n_in,
                              void* d_out, int out_size, void* d_ws, size_t ws_size,
                              hipStream_t stream) {
  (void)in_sizes; (void)n_in; (void)out_size;
  const float* q = (const float*)d_in[0];
  const float* k = (const float*)d_in[1];
  const float* v = (const float*)d_in[2];
  const int* flag = (const int*)d_in[3];
  float* out = (float*)d_out;
  if (ws_size >= WS_NEED) {
    char* ws = (char*)d_ws;
    prep_kernel<<<dim3(1024), dim3(256), 0, stream>>>(k, v, ws);
    fattn_kernel<<<dim3(512), dim3(256), 0, stream>>>(q, ws, flag, out);
  } else {
    fattn_fb<<<dim3(512), dim3(256), 0, stream>>>(q, k, v, flag, out);
  }
}